// Round 6
// baseline (356.136 us; speedup 1.0000x reference)
//
#include <hip/hip_runtime.h>

typedef unsigned int u32;
typedef unsigned long long u64;

// ---------------------------------------------------------------------------
// Exact reproduction of (VERIFIED bit-exact in rounds 3/4/5):
//   u    = jax.random.uniform(jax.random.key(42), (256,1024,256))
//          [threefry2x32, jax_threefry_partitionable=True 32-bit path:
//           elem i = (w0 ^ w1) of threefry2x32_20(key=(0,42), block=(0,i))]
//   rank = argsort(argsort(u, -1), -1)      (stable -> lex order on (value,idx))
//   n1   = round_half_even(x * 256)
//   out  = (rank < n1) ? 1.0f : 0.0f
//
// R6: scalarize the select-loop bookkeeping. R5 measured ~161us; issue-count
// model says select ran with VECTOR bookkeeping (v_bcnt/v_add/v_cndmask) and
// a dead early-exit (~31 iters, ~3720cy/wave) on top of the 2432cy PRNG.
// Fix: s_bcnt1_i32_b64 via inline asm pins cnt/T/done into SGPRs -> per iter
// only 16 v_cmp hit the VALU port; SALU co-issues; break is s_cbranch with
// ~11 expected iters. PRNG & selection math untouched (bit-exact verified).
// ---------------------------------------------------------------------------

#define ROTL(x, r) __builtin_amdgcn_alignbit((x), (x), 32u - (r))

// Threefry-2x32, 20 rounds, key (0, 42), block (0, i). Returns w0 ^ w1.
__device__ __forceinline__ u32 threefry_xor(u32 i) {
  const u32 ks0 = 0u;
  const u32 ks1 = 42u;
  const u32 ks2 = 0x1BD11BF0u;   // 0x1BD11BDA ^ 0 ^ 42
  u32 x0 = 0u + ks0;
  u32 x1 = i + ks1;
#define TFR(r) { x0 += x1; x1 = ROTL(x1, r##u); x1 ^= x0; }
  TFR(13) TFR(15) TFR(26) TFR(6)
  x0 += ks1; x1 += ks2 + 1u;
  TFR(17) TFR(29) TFR(16) TFR(24)
  x0 += ks2; x1 += ks0 + 2u;
  TFR(13) TFR(15) TFR(26) TFR(6)
  x0 += ks0; x1 += ks1 + 3u;
  TFR(17) TFR(29) TFR(16) TFR(24)
  x0 += ks1; x1 += ks2 + 4u;
  TFR(13) TFR(15) TFR(26) TFR(6)
  x0 += ks2; x1 += ks0 + 5u;
#undef TFR
  return x0 ^ x1;
}

// Wave-wide popcount of a predicate, FORCED into the scalar domain:
// ballot lands in an SGPR pair; s_bcnt1_i32_b64 keeps the count scalar.
__device__ __forceinline__ u32 bcnt(int pred) {
  u64 m = __ballot(pred);
  u32 c;
  asm("s_bcnt1_i32_b64 %0, %1" : "=s"(c) : "s"(m) : "scc");
  return c;
}

// One wave64 owns FOUR rows of 256 bits; lane owns bits b = 4*lane + {0..3}
// of each row. Key K = bits[31:9]<<8 | b  (31-bit, distinct within a row).
__global__ __launch_bounds__(256) void bitinput_kernel(
    const float* __restrict__ x, float* __restrict__ out, int nrows) {
  const int lane  = threadIdx.x & 63;
  const int wid   = threadIdx.x >> 6;
  const int row0  = ((blockIdx.x << 2) + wid) << 2;   // 4 rows per wave
  if (row0 >= nrows) return;

  const u32 idx0 = (u32)lane << 2;                    // elem index within row

  // ---- PRNG: 16 chains; pack distinct keys K = (m23<<8)|idx ----
  u32 K[4][4];
#pragma unroll
  for (int r = 0; r < 4; ++r) {
    const u32 gbase = ((u32)(row0 + r)) << 8;         // flat element index base
#pragma unroll
    for (int k = 0; k < 4; ++k) {
      const u32 b = idx0 + (u32)k;
      K[r][k] = ((threefry_xor(gbase + b) >> 1) & 0x7FFFFF00u) | b;
    }
  }

  // n1_r = round-half-even(x*256); exact in f32. Wave-uniform scalars.
  const u32 n1_0 = (u32)__builtin_amdgcn_readfirstlane((int)rintf(x[row0 + 0] * 256.0f));
  const u32 n1_1 = (u32)__builtin_amdgcn_readfirstlane((int)rintf(x[row0 + 1] * 256.0f));
  const u32 n1_2 = (u32)__builtin_amdgcn_readfirstlane((int)rintf(x[row0 + 2] * 256.0f));
  const u32 n1_3 = (u32)__builtin_amdgcn_readfirstlane((int)rintf(x[row0 + 3] * 256.0f));

  // ---- 4 interleaved radix searches; bookkeeping pinned to SALU ----
  // Invariant: T = greatest prefix with count_less(T) <= n1; freeze on clean
  // cut cnt==n1 (then sel = K<T), else T ends at K_(n1-1) (then sel = K<=T).
  u32 T0 = 0u, T1 = 0u, T2 = 0u, T3 = 0u;
  u32 d0 = 0u, d1 = 0u, d2 = 0u, d3 = 0u;    // done flags (0/1)
#pragma unroll 1
  for (int bit = 30; bit >= 0; --bit) {
    const u32 b = 1u << bit;
    {
      const u32 mid = T0 | b;
      const u32 cnt = bcnt(K[0][0] < mid) + bcnt(K[0][1] < mid)
                    + bcnt(K[0][2] < mid) + bcnt(K[0][3] < mid);
      const u32 ok  = (u32)((d0 == 0u) & (cnt <= n1_0));
      T0 |= b & (0u - ok);
      d0 |= (u32)(cnt == n1_0);
    }
    {
      const u32 mid = T1 | b;
      const u32 cnt = bcnt(K[1][0] < mid) + bcnt(K[1][1] < mid)
                    + bcnt(K[1][2] < mid) + bcnt(K[1][3] < mid);
      const u32 ok  = (u32)((d1 == 0u) & (cnt <= n1_1));
      T1 |= b & (0u - ok);
      d1 |= (u32)(cnt == n1_1);
    }
    {
      const u32 mid = T2 | b;
      const u32 cnt = bcnt(K[2][0] < mid) + bcnt(K[2][1] < mid)
                    + bcnt(K[2][2] < mid) + bcnt(K[2][3] < mid);
      const u32 ok  = (u32)((d2 == 0u) & (cnt <= n1_2));
      T2 |= b & (0u - ok);
      d2 |= (u32)(cnt == n1_2);
    }
    {
      const u32 mid = T3 | b;
      const u32 cnt = bcnt(K[3][0] < mid) + bcnt(K[3][1] < mid)
                    + bcnt(K[3][2] < mid) + bcnt(K[3][3] < mid);
      const u32 ok  = (u32)((d3 == 0u) & (cnt <= n1_3));
      T3 |= b & (0u - ok);
      d3 |= (u32)(cnt == n1_3);
    }
    if ((d0 & d1 & d2 & d3) != 0u) break;   // uniform -> s_cbranch
  }

  // ---- emit: done -> K < T (clean cut); else K <= T (T = K_(n1-1)) ----
  const u32 Ts[4] = { d0 ? T0 : (T0 + 1u), d1 ? T1 : (T1 + 1u),
                      d2 ? T2 : (T2 + 1u), d3 ? T3 : (T3 + 1u) };
#pragma unroll
  for (int r = 0; r < 4; ++r) {
    float4 o;
    o.x = (K[r][0] < Ts[r]) ? 1.0f : 0.0f;
    o.y = (K[r][1] < Ts[r]) ? 1.0f : 0.0f;
    o.z = (K[r][2] < Ts[r]) ? 1.0f : 0.0f;
    o.w = (K[r][3] < Ts[r]) ? 1.0f : 0.0f;
    reinterpret_cast<float4*>(out)[((row0 + r) << 6) + lane] = o;
  }
}

extern "C" void kernel_launch(void* const* d_in, const int* in_sizes, int n_in,
                              void* d_out, int out_size, void* d_ws, size_t ws_size,
                              hipStream_t stream) {
  const float* x = (const float*)d_in[0];
  float* out = (float*)d_out;
  const int nrows = in_sizes[0];                 // 256*1024 = 262144 bitstreams
  // 4 waves/block, 4 rows/wave -> 16 rows/block
  const int blocks = (nrows + 15) >> 4;
  hipLaunchKernelGGL(bitinput_kernel, dim3(blocks), dim3(256), 0, stream,
                     x, out, nrows);
}

// Round 7
// 338.561 us; speedup vs baseline: 1.0519x; 1.0519x over previous
//
#include <hip/hip_runtime.h>

typedef unsigned int u32;
typedef unsigned long long u64;

// ---------------------------------------------------------------------------
// Exact reproduction of (VERIFIED bit-exact in rounds 3-6):
//   u    = jax.random.uniform(jax.random.key(42), (256,1024,256))
//          [threefry2x32, jax_threefry_partitionable=True 32-bit path:
//           elem i = (w0 ^ w1) of threefry2x32_20(key=(0,42), block=(0,i))]
//   rank = argsort(argsort(u, -1), -1)      (stable -> lex order on (value,idx))
//   n1   = round_half_even(x * 256)
//   out  = (rank < n1) ? 1.0f : 0.0f
//
// R7: kill register pressure. R6 measured 179 VALU-instr/elem vs ~100 static
// at VGPR_Count=16 -- 16 live K's can't fit 16 arch VGPRs, no scratch traffic
// => compiler is shuttling through AGPRs (v_accvgpr_*, each a VALU instr,
// invisible in VGPR_Count). Fix: 1 row/wave, 4 elems/lane (K[4]+temps ~12
// VGPRs). Select math unchanged. Key pack now 32-bit: K = (w & ~0x1FF) | b
// (same order as (w>>9, b) lex since b < 512; 1 v_and_or_b32).
// ---------------------------------------------------------------------------

#define ROTL(x, r) __builtin_amdgcn_alignbit((x), (x), 32u - (r))

// Threefry-2x32, 20 rounds, key (0, 42), block (0, i). Returns w0 ^ w1.
__device__ __forceinline__ u32 threefry_xor(u32 i) {
  const u32 ks0 = 0u;
  const u32 ks1 = 42u;
  const u32 ks2 = 0x1BD11BF0u;   // 0x1BD11BDA ^ 0 ^ 42
  u32 x0 = 0u + ks0;
  u32 x1 = i + ks1;
#define TFR(r) { x0 += x1; x1 = ROTL(x1, r##u); x1 ^= x0; }
  TFR(13) TFR(15) TFR(26) TFR(6)
  x0 += ks1; x1 += ks2 + 1u;
  TFR(17) TFR(29) TFR(16) TFR(24)
  x0 += ks2; x1 += ks0 + 2u;
  TFR(13) TFR(15) TFR(26) TFR(6)
  x0 += ks0; x1 += ks1 + 3u;
  TFR(17) TFR(29) TFR(16) TFR(24)
  x0 += ks1; x1 += ks2 + 4u;
  TFR(13) TFR(15) TFR(26) TFR(6)
  x0 += ks2; x1 += ks0 + 5u;
#undef TFR
  return x0 ^ x1;
}

// Wave-wide popcount of a predicate, pinned to the scalar domain.
__device__ __forceinline__ u32 bcnt(int pred) {
  u64 m = __ballot(pred);
  u32 c;
  asm("s_bcnt1_i32_b64 %0, %1" : "=s"(c) : "s"(m) : "scc");
  return c;
}

// One wave64 per row of 256 bits; lane owns bits b = 4*lane + {0..3}.
// Key K = (w & 0xFFFFFE00) | b : 32-bit, distinct, lex order == (u, idx).
__global__ __launch_bounds__(256) void bitinput_kernel(
    const float* __restrict__ x, float* __restrict__ out, int nrows) {
  const int lane = threadIdx.x & 63;
  const int wid  = threadIdx.x >> 6;
  const int row  = (blockIdx.x << 2) + wid;
  if (row >= nrows) return;

  const u32 gbase = ((u32)row) << 8;       // flat element index base (uniform)
  const u32 ci    = gbase + ((u32)lane << 2);

  // ---- PRNG: 4 chains; 32-bit distinct keys ----
  const u32 b0 = (u32)(lane << 2);
  u32 K0 = (threefry_xor(ci + 0u) & 0xFFFFFE00u) | (b0 + 0u);
  u32 K1 = (threefry_xor(ci + 1u) & 0xFFFFFE00u) | (b0 + 1u);
  u32 K2 = (threefry_xor(ci + 2u) & 0xFFFFFE00u) | (b0 + 2u);
  u32 K3 = (threefry_xor(ci + 3u) & 0xFFFFFE00u) | (b0 + 3u);

  // n1 = round-half-even(x*256); exact in f32; wave-uniform scalar.
  const u32 n1 = (u32)__builtin_amdgcn_readfirstlane((int)rintf(x[row] * 256.0f));

  // ---- radix search, bits 31..0; scalar bookkeeping ----
  // Invariant: T = greatest prefix with count_less(T) <= n1; freeze on clean
  // cut cnt==n1 (then sel = K<T), else T ends at K_(n1-1) (then sel = K<=T).
  u32 T = 0u, done = 0u;
#pragma unroll 1
  for (int bit = 31; bit >= 0; --bit) {
    const u32 mid = T | (1u << bit);
    const u32 cnt = bcnt(K0 < mid) + bcnt(K1 < mid)
                  + bcnt(K2 < mid) + bcnt(K3 < mid);
    const u32 ok  = (u32)((done == 0u) & (cnt <= n1));
    T |= (1u << bit) & (0u - ok);
    done |= (u32)(cnt == n1);
    if (done) break;                        // uniform -> s_cbranch
  }

  // ---- emit: done -> K < T (clean cut); else K <= T (T = K_(n1-1)) ----
  u32 Tsel = done ? T : (T + 1u);
  if (n1 == 0u) Tsel = 0u;   // guard: never-done fallthrough would pick K_min
  float4 o;
  o.x = (K0 < Tsel) ? 1.0f : 0.0f;
  o.y = (K1 < Tsel) ? 1.0f : 0.0f;
  o.z = (K2 < Tsel) ? 1.0f : 0.0f;
  o.w = (K3 < Tsel) ? 1.0f : 0.0f;
  reinterpret_cast<float4*>(out)[(int)(gbase >> 2) + lane] = o;
}

extern "C" void kernel_launch(void* const* d_in, const int* in_sizes, int n_in,
                              void* d_out, int out_size, void* d_ws, size_t ws_size,
                              hipStream_t stream) {
  const float* x = (const float*)d_in[0];
  float* out = (float*)d_out;
  const int nrows = in_sizes[0];                 // 256*1024 = 262144 bitstreams
  const int blocks = (nrows + 3) >> 2;           // 4 waves (rows) per block
  hipLaunchKernelGGL(bitinput_kernel, dim3(blocks), dim3(256), 0, stream,
                     x, out, nrows);
}

// Round 8
// 338.288 us; speedup vs baseline: 1.0528x; 1.0008x over previous
//
#include <hip/hip_runtime.h>

typedef unsigned int u32;
typedef unsigned long long u64;

// ---------------------------------------------------------------------------
// Exact reproduction of (VERIFIED bit-exact in rounds 3-7):
//   u    = jax.random.uniform(jax.random.key(42), (256,1024,256))
//          [threefry2x32, jax_threefry_partitionable=True 32-bit path:
//           elem i = (w0 ^ w1) of threefry2x32_20(key=(0,42), block=(0,i))]
//   rank = argsort(argsort(u, -1), -1)      (stable -> lex order on (value,idx))
//   n1   = round_half_even(x * 256)
//   out  = (rank < n1) ? 1.0f : 0.0f
//
// R8: kill the __ballot materialization tax. HIP __ballot(pred) lowers as
// icmp_ne(zext(pred)) -> v_cmp + v_cndmask + v_cmp = 3 VALU per ballot; at
// 4 ballots/iter over ~25 iters that was ~300 VALU/wave -- the exact gap
// between the 648 measured and ~370 modeled instrs (and why R3-R7 all tied).
// Fix: single-instruction compare-to-sgpr via inline asm:
//       v_cmp_gt_u32 s[pair], s_mid, v_K     (mid > K  <=>  K < mid)
// then s_bcnt1_i32_b64. Select iter cost: exactly 4 VALU + ~13 SALU.
// PRNG, selection invariant, tie-free key pack: unchanged from verified R7.
// ---------------------------------------------------------------------------

#define ROTL(x, r) __builtin_amdgcn_alignbit((x), (x), 32u - (r))

// Threefry-2x32, 20 rounds, key (0, 42), block (0, i). Returns w0 ^ w1.
__device__ __forceinline__ u32 threefry_xor(u32 i) {
  const u32 ks0 = 0u;
  const u32 ks1 = 42u;
  const u32 ks2 = 0x1BD11BF0u;   // 0x1BD11BDA ^ 0 ^ 42
  u32 x0 = 0u + ks0;
  u32 x1 = i + ks1;
#define TFR(r) { x0 += x1; x1 = ROTL(x1, r##u); x1 ^= x0; }
  TFR(13) TFR(15) TFR(26) TFR(6)
  x0 += ks1; x1 += ks2 + 1u;
  TFR(17) TFR(29) TFR(16) TFR(24)
  x0 += ks2; x1 += ks0 + 2u;
  TFR(13) TFR(15) TFR(26) TFR(6)
  x0 += ks0; x1 += ks1 + 3u;
  TFR(17) TFR(29) TFR(16) TFR(24)
  x0 += ks1; x1 += ks2 + 4u;
  TFR(13) TFR(15) TFR(26) TFR(6)
  x0 += ks2; x1 += ks0 + 5u;
#undef TFR
  return x0 ^ x1;
}

// count_less: #lanes with K < mid (mid wave-uniform), 1 VALU + 1 SALU.
// v_cmp writes the 64-bit lane mask straight into an SGPR pair; s_bcnt1
// counts it. No bool->int materialization, no v_cndmask.
__device__ __forceinline__ u32 cnt_lt(u32 K, u32 mid) {
  u64 m;
  asm("v_cmp_gt_u32 %0, %1, %2" : "=s"(m) : "s"(mid), "v"(K));
  u32 c;
  asm("s_bcnt1_i32_b64 %0, %1" : "=s"(c) : "s"(m) : "scc");
  return c;
}

// One wave64 per row of 256 bits; lane owns bits b = 4*lane + {0..3}.
// Key K = (w & 0xFFFFFE00) | b : 32-bit, distinct, lex order == (u, idx).
__global__ __launch_bounds__(256) void bitinput_kernel(
    const float* __restrict__ x, float* __restrict__ out, int nrows) {
  const int lane = threadIdx.x & 63;
  const int wid  = threadIdx.x >> 6;
  const int row  = (blockIdx.x << 2) + wid;
  if (row >= nrows) return;

  const u32 gbase = ((u32)row) << 8;       // flat element index base (uniform)
  const u32 ci    = gbase + ((u32)lane << 2);

  // ---- PRNG: 4 chains; 32-bit distinct keys ----
  const u32 b0 = (u32)(lane << 2);
  u32 K0 = (threefry_xor(ci + 0u) & 0xFFFFFE00u) | (b0 + 0u);
  u32 K1 = (threefry_xor(ci + 1u) & 0xFFFFFE00u) | (b0 + 1u);
  u32 K2 = (threefry_xor(ci + 2u) & 0xFFFFFE00u) | (b0 + 2u);
  u32 K3 = (threefry_xor(ci + 3u) & 0xFFFFFE00u) | (b0 + 3u);

  // n1 = round-half-even(x*256); exact in f32; wave-uniform scalar.
  const u32 n1 = (u32)__builtin_amdgcn_readfirstlane((int)rintf(x[row] * 256.0f));

  // ---- radix search, bits 31..0; scalar bookkeeping ----
  // Invariant: T = greatest prefix with count_less(T) <= n1; freeze on clean
  // cut cnt==n1 (then sel = K<T), else T ends at K_(n1-1) (then sel = K<=T).
  u32 T = 0u, done = 0u;
#pragma unroll 1
  for (int bit = 31; bit >= 0; --bit) {
    const u32 mid = T | (1u << bit);
    const u32 cnt = cnt_lt(K0, mid) + cnt_lt(K1, mid)
                  + cnt_lt(K2, mid) + cnt_lt(K3, mid);
    const u32 ok  = (u32)((done == 0u) & (cnt <= n1));
    T |= (1u << bit) & (0u - ok);
    done |= (u32)(cnt == n1);
    if (done) break;                        // uniform -> s_cbranch
  }

  // ---- emit: done -> K < T (clean cut); else K <= T (T = K_(n1-1)) ----
  u32 Tsel = done ? T : (T + 1u);
  if (n1 == 0u) Tsel = 0u;   // guard: never-done fallthrough would pick K_min
  float4 o;
  o.x = (K0 < Tsel) ? 1.0f : 0.0f;
  o.y = (K1 < Tsel) ? 1.0f : 0.0f;
  o.z = (K2 < Tsel) ? 1.0f : 0.0f;
  o.w = (K3 < Tsel) ? 1.0f : 0.0f;
  reinterpret_cast<float4*>(out)[(int)(gbase >> 2) + lane] = o;
}

extern "C" void kernel_launch(void* const* d_in, const int* in_sizes, int n_in,
                              void* d_out, int out_size, void* d_ws, size_t ws_size,
                              hipStream_t stream) {
  const float* x = (const float*)d_in[0];
  float* out = (float*)d_out;
  const int nrows = in_sizes[0];                 // 256*1024 = 262144 bitstreams
  const int blocks = (nrows + 3) >> 2;           // 4 waves (rows) per block
  hipLaunchKernelGGL(bitinput_kernel, dim3(blocks), dim3(256), 0, stream,
                     x, out, nrows);
}